// Round 2
// baseline (73.243 us; speedup 1.0000x reference)
//
#include <hip/hip_runtime.h>
#include <stdint.h>

#define DIMS   1000
#define NLEV   10
#define NPIX   784
#define NBATCH 256
#define NCLS   10
#define WPD    32      // u32 words per dim-row (32*32 = 1024 >= 1000)

// ---------------------------------------------------------------------------
// Kernel 1: ballot-pack sign bits. One wave per row; 64 lanes load 64
// consecutive floats (coalesced), __ballot forms 64 bits -> one u64 store.
// Rows 0..783 = position, 784..793 = value_table (contiguous in ws).
// ---------------------------------------------------------------------------
__global__ __launch_bounds__(256) void pack_ballot(const float* __restrict__ position,
                                                   const float* __restrict__ value_table,
                                                   uint64_t* __restrict__ ws64) {
    const int t    = threadIdx.x;
    const int lane = t & 63;
    const int wv   = (blockIdx.x * 256 + t) >> 6;
    const int nw   = (gridDim.x * 256) >> 6;
    for (int r = wv; r < NPIX + NLEV; r += nw) {
        const float* src = (r < NPIX) ? (position + (size_t)r * DIMS)
                                      : (value_table + (size_t)(r - NPIX) * DIMS);
        #pragma unroll
        for (int k = 0; k < 16; ++k) {           // 16*64 = 1024 >= 1000
            int d = k * 64 + lane;
            float v = (d < DIMS) ? src[d] : 0.f; // pad bits -> 0 (harmless)
            uint64_t m = __ballot(v > 0.f);
            if (lane == 0) ws64[(size_t)r * 16 + k] = m;
        }
    }
}

// full adder on bit-planes: sum/carry of a+b+cin (5 ops)
__device__ __forceinline__ void fa(uint32_t a, uint32_t b, uint32_t cin,
                                   uint32_t& s, uint32_t& c) {
    uint32_t t = a ^ b;
    s = t ^ cin;
    c = (a & b) | (t & cin);
}

// ---------------------------------------------------------------------------
// Kernel 2: one block per batch element, 512 threads.
// lane role: w = t&31 (dim word), g = t>>5 (pixel group, 16 groups x 49 pix).
// Count per-dim MISMATCH bits (pos^vt) with a CSA tree into 6 bit-planes,
// merge the wave's two groups via shuffle, then ONE single-wave bit-sliced
// accumulate over the 8 merged groups (plane-major LDS, conflict-free),
// bitwise threshold, tiny logit GEMV with pre-hoisted W registers.
// ---------------------------------------------------------------------------
__global__ __launch_bounds__(512) void hdc_main(const float* __restrict__ x,
                                                const float* __restrict__ W,
                                                const uint32_t* __restrict__ ws_bits,
                                                float* __restrict__ out) {
    __shared__ uint32_t s_idx[NPIX];             // 3136 B
    __shared__ uint32_t s_vt[NLEV * WPD];        // 1280 B
    __shared__ uint32_t s_cnt1[7 * 256];         // 7168 B, PLANE-major: [plane][wid*32+w]
    __shared__ uint32_t s_enc[32];               //  128 B (enc bits per word)
    __shared__ float    s_red[8][NCLS];          //  320 B

    const int b    = blockIdx.x;
    const int t    = threadIdx.x;
    const int lane = t & 63;
    const int wid  = t >> 6;

    // ---- hoisted classifier weights: L2/HBM latency hides under everything
    float2 wreg[NCLS];
    if (t < 500) {
        #pragma unroll
        for (int cc = 0; cc < NCLS; ++cc)
            wreg[cc] = *(const float2*)(W + cc * DIMS + 2 * t);
    }

    // --- per-pixel level index: idx = clip(rint(x*9), 0, 9)
    for (int p = t; p < NPIX; p += 512) {
        float v = x[b * NPIX + p] * 9.0f;
        int l = (int)rintf(v);                   // half-even, matches jnp.round
        l = l < 0 ? 0 : (l > 9 ? 9 : l);
        s_idx[p] = (uint32_t)(l * WPD);          // pre-scaled row offset
    }
    if (t < NLEV * WPD) s_vt[t] = ws_bits[NPIX * WPD + t];
    __syncthreads();

    const int w = t & 31;                        // dim word
    const int g = t >> 5;                        // pixel group (16 groups x 49 pix)

    uint32_t p0 = 0, p1 = 0, p2 = 0, p3 = 0, p4 = 0, p5 = 0;

    // 2-stage prefetch pipeline on the position-bit loads (L2 hits)
    uint32_t posn[8];
    #pragma unroll
    for (int j = 0; j < 8; ++j)
        posn[j] = ws_bits[(g + 16 * j) * WPD + w];

    // pixels for group g: pl = g + 16*k, k = 0..48  (49 pixels, 6 chunks of 8 + 1)
    for (int c = 0; c < 6; ++c) {
        uint32_t posv[8];
        #pragma unroll
        for (int j = 0; j < 8; ++j) posv[j] = posn[j];
        if (c < 5) {
            #pragma unroll
            for (int j = 0; j < 8; ++j)
                posn[j] = ws_bits[(g + 128 * (c + 1) + 16 * j) * WPD + w];
        }
        uint32_t xv[8];
        #pragma unroll
        for (int j = 0; j < 8; ++j)
            xv[j] = posv[j] ^ s_vt[s_idx[g + 128 * c + 16 * j] + w];  // mismatch bits
        // CSA tree: 8 inputs -> planes
        uint32_t sa, ca, sb, cb, sc, cc, cd, se, ce, cf, cg2;
        fa(xv[0], xv[1], xv[2], sa, ca);
        fa(xv[3], xv[4], xv[5], sb, cb);
        fa(xv[6], xv[7], p0,   sc, cc);
        fa(sa, sb, sc, p0, cd);          // new ones plane
        fa(ca, cb, cc, se, ce);
        fa(se, cd, p1, p1, cf);          // new twos plane
        fa(ce, cf, p2, p2, cg2);         // new fours plane
        uint32_t tmp = p3 & cg2; p3 ^= cg2;        // ripple weight-8 carry
        uint32_t tm2 = p4 & tmp; p4 ^= tmp;
        p5 ^= tm2;
    }
    {   // tail pixel: pl = g + 768
        uint32_t xb = ws_bits[(g + 768) * WPD + w] ^ s_vt[s_idx[g + 768] + w];
        uint32_t c = xb, tmp;
        tmp = p0 & c; p0 ^= c; c = tmp;
        tmp = p1 & c; p1 ^= c; c = tmp;
        tmp = p2 & c; p2 ^= c; c = tmp;
        tmp = p3 & c; p3 ^= c; c = tmp;
        tmp = p4 & c; p4 ^= c; c = tmp;
        p5 ^= c;
    }

    // --- merge the wave's two groups via shuffle: lanes 0..31 get g, 32..63 hold g+1
    {
        uint32_t q0 = __shfl_down(p0, 32), q1 = __shfl_down(p1, 32),
                 q2 = __shfl_down(p2, 32), q3 = __shfl_down(p3, 32),
                 q4 = __shfl_down(p4, 32), q5 = __shfl_down(p5, 32);
        // 6-plane + 6-plane -> 7-plane bit-sliced add (lanes<32 meaningful)
        uint32_t r0, r1, r2, r3, r4, r5, r6, c, tt;
        c  = p0 & q0; r0 = p0 ^ q0;
        tt = p1 ^ q1; r1 = tt ^ c; c = (p1 & q1) | (tt & c);
        tt = p2 ^ q2; r2 = tt ^ c; c = (p2 & q2) | (tt & c);
        tt = p3 ^ q3; r3 = tt ^ c; c = (p3 & q3) | (tt & c);
        tt = p4 ^ q4; r4 = tt ^ c; c = (p4 & q4) | (tt & c);
        tt = p5 ^ q5; r5 = tt ^ c; c = (p5 & q5) | (tt & c);
        r6 = c;
        if ((t & 63) < 32) {
            // plane-major layout: lane stride 1 -> conflict-free writes AND reads
            int base = wid * 32 + w;
            s_cnt1[0 * 256 + base] = r0; s_cnt1[1 * 256 + base] = r1;
            s_cnt1[2 * 256 + base] = r2; s_cnt1[3 * 256 + base] = r3;
            s_cnt1[4 * 256 + base] = r4; s_cnt1[5 * 256 + base] = r5;
            s_cnt1[6 * 256 + base] = r6;
        }
    }
    __syncthreads();

    // --- single-wave final reduce: 8 groups x 7 planes -> 10-plane count,
    //     then bitwise threshold. Replaces 3 barrier-separated tree rounds.
    // m[d] = mismatch count; enc = +1 iff matches > 392 iff m <= 391
    // carry-out of (m + 632) over 10 bits == (m >= 392); enc = ~carry
    if (t < 32) {
        uint32_t acc[10];
        #pragma unroll
        for (int i = 0; i < 7; ++i) acc[i] = s_cnt1[i * 256 + t];
        acc[7] = acc[8] = acc[9] = 0u;
        #pragma unroll
        for (int gg = 1; gg < 8; ++gg) {
            uint32_t c = 0, tt;
            #pragma unroll
            for (int i = 0; i < 7; ++i) {
                uint32_t a = acc[i], bv = s_cnt1[i * 256 + gg * 32 + t];
                tt = a ^ bv;
                acc[i] = tt ^ c;
                c = (a & bv) | (tt & c);
            }
            #pragma unroll
            for (int i = 7; i < 10; ++i) {       // propagate carry into high planes
                uint32_t a = acc[i];
                acc[i] = a ^ c;
                c = a & c;
            }
        }
        // 632 = 0b1001111000 : bits 3,4,5,6,9 set
        uint32_t cy = acc[3];                 // k=1, cin was 0 -> maj = a
        cy = acc[4] | cy;                     // k=1
        cy = acc[5] | cy;                     // k=1
        cy = acc[6] | cy;                     // k=1
        cy = acc[7] & cy;                     // k=0
        cy = acc[8] & cy;                     // k=0
        cy = acc[9] | cy;                     // k=1
        s_enc[t] = ~cy;                       // enc bit = 1 -> +1
    }
    __syncthreads();

    // --- logits: 500 threads x 2 dims, +-W from pre-hoisted regs, shuffle reduce
    float partial[NCLS];
    #pragma unroll
    for (int cc = 0; cc < NCLS; ++cc) partial[cc] = 0.f;

    if (t < 500) {
        int d0 = 2 * t;
        uint32_t ew = s_enc[d0 >> 5];
        float e0 = ((ew >> (d0 & 31)) & 1u) ? 1.0f : -1.0f;
        float e1 = ((ew >> ((d0 + 1) & 31)) & 1u) ? 1.0f : -1.0f;  // same word (d0 even)
        #pragma unroll
        for (int cc = 0; cc < NCLS; ++cc)
            partial[cc] = e0 * wreg[cc].x + e1 * wreg[cc].y;
    }
    #pragma unroll
    for (int cc = 0; cc < NCLS; ++cc) {
        #pragma unroll
        for (int off = 32; off > 0; off >>= 1)
            partial[cc] += __shfl_down(partial[cc], off);
    }
    if (lane == 0) {
        #pragma unroll
        for (int cc = 0; cc < NCLS; ++cc) s_red[wid][cc] = partial[cc];
    }
    __syncthreads();
    if (t < NCLS) {
        float acc = 0.f;
        #pragma unroll
        for (int v = 0; v < 8; ++v) acc += s_red[v][t];
        out[b * NCLS + t] = acc;
    }
}

extern "C" void kernel_launch(void* const* d_in, const int* in_sizes, int n_in,
                              void* d_out, int out_size, void* d_ws, size_t ws_size,
                              hipStream_t stream) {
    const float* x        = (const float*)d_in[0];  // [256,28,28]
    const float* position = (const float*)d_in[1];  // [784,1000]
    const float* vtab     = (const float*)d_in[2];  // [10,1000]
    const float* W        = (const float*)d_in[3];  // [10,1000]
    float* out            = (float*)d_out;          // [256,10]

    pack_ballot<<<200, 256, 0, stream>>>(position, vtab, (uint64_t*)d_ws);
    hdc_main<<<NBATCH, 512, 0, stream>>>(x, W, (const uint32_t*)d_ws, out);
}